// Round 1
// baseline (123.757 us; speedup 1.0000x reference)
//
#include <hip/hip_runtime.h>

#define K_OFF 27
#define INC 32
#define OUTC 64

typedef short bf16x8 __attribute__((ext_vector_type(8)));
typedef float f32x4 __attribute__((ext_vector_type(4)));

__device__ __forceinline__ short f2bf(float f) {
  union { float f; unsigned u; } v; v.f = f;
  unsigned u = v.u;
  unsigned r = (u + 0x7FFFu + ((u >> 16) & 1u)) >> 16;
  return (short)(r & 0xFFFFu);
}

// Pre-kernel 1: features fp32 -> bf16 (row-major [N][32], rows stay 64B)
__global__ void cvt_features(const float* __restrict__ feat,
                             short* __restrict__ wsF, int total8) {
  int c = blockIdx.x * blockDim.x + threadIdx.x;  // one 8-elem chunk each
  if (c >= total8) return;
  const float4* fp = (const float4*)feat + (size_t)c * 2;
  float4 f0 = fp[0], f1 = fp[1];
  bf16x8 o;
  o[0] = f2bf(f0.x); o[1] = f2bf(f0.y); o[2] = f2bf(f0.z); o[3] = f2bf(f0.w);
  o[4] = f2bf(f1.x); o[5] = f2bf(f1.y); o[6] = f2bf(f1.z); o[7] = f2bf(f1.w);
  ((bf16x8*)wsF)[c] = o;
}

// Pre-kernel 2: weights fp32 [27][32][64] -> bf16 B-fragments
// wsB layout: [(k*4 + tile)*64 + lane] -> 8 bf16 (lane: col=lane&15 of tile,
// k-elems = (lane>>4)*8 + j), so the main kernel loads each B-frag as one 16B read.
__global__ void cvt_weights(const float* __restrict__ w, short* __restrict__ wsB) {
  int k = blockIdx.x;
  int t = threadIdx.x >> 6;
  int lane = threadIdx.x & 63;
  int khalf = lane >> 4, c = lane & 15;
  bf16x8 o;
#pragma unroll
  for (int j = 0; j < 8; ++j) {
    float val = w[((k * INC) + (khalf * 8 + j)) * OUTC + t * 16 + c];
    o[j] = f2bf(val);
  }
  ((bf16x8*)wsB)[(k * 4 + t) * 64 + lane] = o;
}

// Main kernel: one wave = 16 output points, all 64 output channels.
// MODE 2: bf16 features from ws + bf16 B-frags from ws
// MODE 1: fp32 features (inline convert) + bf16 B-frags from ws
// MODE 0: fully standalone (inline strided weight loads)
template <int MODE>
__global__ __launch_bounds__(256) void mink_conv(
    const float* __restrict__ feat, const float* __restrict__ w,
    const int* __restrict__ nbr, const short* __restrict__ wsF,
    const short* __restrict__ wsB, float* __restrict__ out, int N) {
  const int lane = threadIdx.x & 63;
  const int wid = threadIdx.x >> 6;
  const int n0 = blockIdx.x * 64 + wid * 16;
  const int r = lane & 15;
  const int khalf = lane >> 4;
  const int n = n0 + r;

  f32x4 acc0 = (f32x4)0.0f, acc1 = (f32x4)0.0f;
  f32x4 acc2 = (f32x4)0.0f, acc3 = (f32x4)0.0f;

  for (int k = 0; k < K_OFF; ++k) {
    int idx = -1;
    if (n < N) idx = nbr[(size_t)k * N + n];

    bf16x8 a = (bf16x8)0;
    if (idx >= 0) {
      if constexpr (MODE == 2) {
        a = *(const bf16x8*)(wsF + (size_t)idx * INC + khalf * 8);
      } else {
        const float4* fp = (const float4*)(feat + (size_t)idx * INC + khalf * 8);
        float4 f0 = fp[0], f1 = fp[1];
        a[0] = f2bf(f0.x); a[1] = f2bf(f0.y); a[2] = f2bf(f0.z); a[3] = f2bf(f0.w);
        a[4] = f2bf(f1.x); a[5] = f2bf(f1.y); a[6] = f2bf(f1.z); a[7] = f2bf(f1.w);
      }
    }

    bf16x8 b0, b1, b2, b3;
    if constexpr (MODE >= 1) {
      const bf16x8* bp = (const bf16x8*)wsB + (size_t)(k * 4) * 64 + lane;
      b0 = bp[0];
      b1 = bp[64];
      b2 = bp[128];
      b3 = bp[192];
    } else {
      const float* wb = w + (size_t)k * INC * OUTC + khalf * 8 * OUTC + (lane & 15);
#pragma unroll
      for (int j = 0; j < 8; ++j) {
        b0[j] = f2bf(wb[j * OUTC + 0]);
        b1[j] = f2bf(wb[j * OUTC + 16]);
        b2[j] = f2bf(wb[j * OUTC + 32]);
        b3[j] = f2bf(wb[j * OUTC + 48]);
      }
    }

    acc0 = __builtin_amdgcn_mfma_f32_16x16x32_bf16(a, b0, acc0, 0, 0, 0);
    acc1 = __builtin_amdgcn_mfma_f32_16x16x32_bf16(a, b1, acc1, 0, 0, 0);
    acc2 = __builtin_amdgcn_mfma_f32_16x16x32_bf16(a, b2, acc2, 0, 0, 0);
    acc3 = __builtin_amdgcn_mfma_f32_16x16x32_bf16(a, b3, acc3, 0, 0, 0);
  }

  // C/D layout: col = lane&15 (within 16-col tile), row = (lane>>4)*4 + j
  const int c = lane & 15;
  const int prow = khalf * 4;
#pragma unroll
  for (int j = 0; j < 4; ++j) {
    int np = n0 + prow + j;
    if (np < N) {
      float* op = out + (size_t)np * OUTC + c;
      op[0] = acc0[j];
      op[16] = acc1[j];
      op[32] = acc2[j];
      op[48] = acc3[j];
    }
  }
}

extern "C" void kernel_launch(void* const* d_in, const int* in_sizes, int n_in,
                              void* d_out, int out_size, void* d_ws, size_t ws_size,
                              hipStream_t stream) {
  const float* feat = (const float*)d_in[0];
  const float* w = (const float*)d_in[1];
  const int* nbr = (const int*)d_in[2];
  float* out = (float*)d_out;

  const int N = in_sizes[0] / INC;

  const size_t featB = (size_t)N * INC * sizeof(short);
  const size_t wB = (size_t)K_OFF * 4 * 64 * 8 * sizeof(short);

  const int blocks = (N + 63) / 64;

  if (ws_size >= featB + wB) {
    short* wsF = (short*)d_ws;
    short* wsB = (short*)d_ws + (size_t)N * INC;
    int total8 = N * INC / 8;
    cvt_features<<<(total8 + 255) / 256, 256, 0, stream>>>(feat, wsF, total8);
    cvt_weights<<<K_OFF, 256, 0, stream>>>(w, wsB);
    mink_conv<2><<<blocks, 256, 0, stream>>>(feat, w, nbr, wsF, wsB, out, N);
  } else if (ws_size >= wB) {
    short* wsB = (short*)d_ws;
    cvt_weights<<<K_OFF, 256, 0, stream>>>(w, wsB);
    mink_conv<1><<<blocks, 256, 0, stream>>>(feat, w, nbr, nullptr, wsB, out, N);
  } else {
    mink_conv<0><<<blocks, 256, 0, stream>>>(feat, w, nbr, nullptr, nullptr, out, N);
  }
}

// Round 2
// 103.985 us; speedup vs baseline: 1.1901x; 1.1901x over previous
//
#include <hip/hip_runtime.h>

#define K_OFF 27
#define INC 32
#define OUTC 64

typedef short bf16x8 __attribute__((ext_vector_type(8)));
typedef float f32x4 __attribute__((ext_vector_type(4)));

__device__ __forceinline__ short f2bf(float f) {
  union { float f; unsigned u; } v; v.f = f;
  unsigned u = v.u;
  unsigned r = (u + 0x7FFFu + ((u >> 16) & 1u)) >> 16;
  return (short)(r & 0xFFFFu);
}

// Pre-kernel 1: features fp32 -> bf16 (row-major [N][32], rows 64B)
__global__ void cvt_features(const float* __restrict__ feat,
                             short* __restrict__ wsF, int total8) {
  int c = blockIdx.x * blockDim.x + threadIdx.x;
  if (c >= total8) return;
  const float4* fp = (const float4*)feat + (size_t)c * 2;
  float4 f0 = fp[0], f1 = fp[1];
  bf16x8 o;
  o[0] = f2bf(f0.x); o[1] = f2bf(f0.y); o[2] = f2bf(f0.z); o[3] = f2bf(f0.w);
  o[4] = f2bf(f1.x); o[5] = f2bf(f1.y); o[6] = f2bf(f1.z); o[7] = f2bf(f1.w);
  ((bf16x8*)wsF)[c] = o;
}

// Pre-kernel 2: weights fp32 [27][32][64] -> bf16 B-fragments.
// wsB[(k*4 + tile)*64 + lane] = 8 bf16: col = lane&15 (of 16-col tile),
// k-elems = (lane>>4)*8 + j. Main kernel loads each B-frag as one 16B read.
__global__ void cvt_weights(const float* __restrict__ w, short* __restrict__ wsB) {
  int k = blockIdx.x;
  int t = threadIdx.x >> 6;
  int lane = threadIdx.x & 63;
  int khalf = lane >> 4, c = lane & 15;
  bf16x8 o;
#pragma unroll
  for (int j = 0; j < 8; ++j) {
    float val = w[((k * INC) + (khalf * 8 + j)) * OUTC + t * 16 + c];
    o[j] = f2bf(val);
  }
  ((bf16x8*)wsB)[(k * 4 + t) * 64 + lane] = o;
}

// Main kernel: one wave = 32 output points (two 16-row MFMA tiles sharing B),
// all 64 output channels. Software-pipelined: idx prefetch distance 2,
// gathered A-frag prefetch distance 1, rotating 2-slot buffers (static idx).
template <int MODE>
__global__ __launch_bounds__(256, 4) void mink_conv(
    const float* __restrict__ feat, const float* __restrict__ w,
    const int* __restrict__ nbr, const short* __restrict__ wsF,
    const short* __restrict__ wsB, float* __restrict__ out, int N) {
  const int lane = threadIdx.x & 63;
  const int wid = threadIdx.x >> 6;
  const int n0 = blockIdx.x * 128 + wid * 32;
  const int r = lane & 15;
  const int khalf = lane >> 4;
  const int nA = n0 + r;
  const int nB = n0 + 16 + r;

  f32x4 accA0 = (f32x4)0.0f, accA1 = (f32x4)0.0f;
  f32x4 accA2 = (f32x4)0.0f, accA3 = (f32x4)0.0f;
  f32x4 accB0 = (f32x4)0.0f, accB1 = (f32x4)0.0f;
  f32x4 accB2 = (f32x4)0.0f, accB3 = (f32x4)0.0f;

  auto ldidx = [&](int k, int n) -> int {
    return (n < N) ? nbr[(size_t)k * N + n] : -1;
  };
  auto gather = [&](int idx) -> bf16x8 {
    bf16x8 a = (bf16x8)0;
    if (idx >= 0) {
      if constexpr (MODE == 2) {
        a = *(const bf16x8*)(wsF + (size_t)idx * INC + khalf * 8);
      } else {
        const float4* fp = (const float4*)(feat + (size_t)idx * INC + khalf * 8);
        float4 f0 = fp[0], f1 = fp[1];
        a[0] = f2bf(f0.x); a[1] = f2bf(f0.y); a[2] = f2bf(f0.z); a[3] = f2bf(f0.w);
        a[4] = f2bf(f1.x); a[5] = f2bf(f1.y); a[6] = f2bf(f1.z); a[7] = f2bf(f1.w);
      }
    }
    return a;
  };

  int iA[2], iB[2];
  bf16x8 aA[2], aB[2];

  // Prologue: idx for k=0,1 in flight; gather k=0.
  iA[0] = ldidx(0, nA); iB[0] = ldidx(0, nB);
  iA[1] = ldidx(1, nA); iB[1] = ldidx(1, nB);
  aA[0] = gather(iA[0]); aB[0] = gather(iB[0]);

#pragma unroll
  for (int k = 0; k < K_OFF; ++k) {
    // Prefetch idx for k+2 (slot (k+2)&1 == k&1; old value consumed at k-1).
    if (k + 2 < K_OFF) {
      iA[k & 1] = ldidx(k + 2, nA);
      iB[k & 1] = ldidx(k + 2, nB);
    }
    // Prefetch gathered A for k+1.
    if (k + 1 < K_OFF) {
      aA[(k + 1) & 1] = gather(iA[(k + 1) & 1]);
      aB[(k + 1) & 1] = gather(iB[(k + 1) & 1]);
    }

    bf16x8 b0, b1, b2, b3;
    if constexpr (MODE >= 1) {
      const bf16x8* bp = (const bf16x8*)wsB + (size_t)(k * 4) * 64 + lane;
      b0 = bp[0];
      b1 = bp[64];
      b2 = bp[128];
      b3 = bp[192];
    } else {
      const float* wb = w + (size_t)k * INC * OUTC + khalf * 8 * OUTC + r;
#pragma unroll
      for (int j = 0; j < 8; ++j) {
        b0[j] = f2bf(wb[j * OUTC + 0]);
        b1[j] = f2bf(wb[j * OUTC + 16]);
        b2[j] = f2bf(wb[j * OUTC + 32]);
        b3[j] = f2bf(wb[j * OUTC + 48]);
      }
    }

    accA0 = __builtin_amdgcn_mfma_f32_16x16x32_bf16(aA[k & 1], b0, accA0, 0, 0, 0);
    accA1 = __builtin_amdgcn_mfma_f32_16x16x32_bf16(aA[k & 1], b1, accA1, 0, 0, 0);
    accA2 = __builtin_amdgcn_mfma_f32_16x16x32_bf16(aA[k & 1], b2, accA2, 0, 0, 0);
    accA3 = __builtin_amdgcn_mfma_f32_16x16x32_bf16(aA[k & 1], b3, accA3, 0, 0, 0);
    accB0 = __builtin_amdgcn_mfma_f32_16x16x32_bf16(aB[k & 1], b0, accB0, 0, 0, 0);
    accB1 = __builtin_amdgcn_mfma_f32_16x16x32_bf16(aB[k & 1], b1, accB1, 0, 0, 0);
    accB2 = __builtin_amdgcn_mfma_f32_16x16x32_bf16(aB[k & 1], b2, accB2, 0, 0, 0);
    accB3 = __builtin_amdgcn_mfma_f32_16x16x32_bf16(aB[k & 1], b3, accB3, 0, 0, 0);
  }

  // C/D layout: col = lane&15, row = (lane>>4)*4 + j (within each 16-row tile)
  const int c = lane & 15;
  const int prow = khalf * 4;
#pragma unroll
  for (int j = 0; j < 4; ++j) {
    int npA = n0 + prow + j;
    if (npA < N) {
      float* op = out + (size_t)npA * OUTC + c;
      op[0] = accA0[j];
      op[16] = accA1[j];
      op[32] = accA2[j];
      op[48] = accA3[j];
    }
    int npB = n0 + 16 + prow + j;
    if (npB < N) {
      float* op = out + (size_t)npB * OUTC + c;
      op[0] = accB0[j];
      op[16] = accB1[j];
      op[32] = accB2[j];
      op[48] = accB3[j];
    }
  }
}

extern "C" void kernel_launch(void* const* d_in, const int* in_sizes, int n_in,
                              void* d_out, int out_size, void* d_ws, size_t ws_size,
                              hipStream_t stream) {
  const float* feat = (const float*)d_in[0];
  const float* w = (const float*)d_in[1];
  const int* nbr = (const int*)d_in[2];
  float* out = (float*)d_out;

  const int N = in_sizes[0] / INC;

  const size_t featB = (size_t)N * INC * sizeof(short);
  const size_t wB = (size_t)K_OFF * 4 * 64 * 8 * sizeof(short);

  const int blocks = (N + 127) / 128;

  if (ws_size >= featB + wB) {
    short* wsF = (short*)d_ws;
    short* wsB = (short*)d_ws + (size_t)N * INC;
    int total8 = N * INC / 8;
    cvt_features<<<(total8 + 255) / 256, 256, 0, stream>>>(feat, wsF, total8);
    cvt_weights<<<K_OFF, 256, 0, stream>>>(w, wsB);
    mink_conv<2><<<blocks, 256, 0, stream>>>(feat, w, nbr, wsF, wsB, out, N);
  } else if (ws_size >= wB) {
    short* wsB = (short*)d_ws;
    cvt_weights<<<K_OFF, 256, 0, stream>>>(w, wsB);
    mink_conv<1><<<blocks, 256, 0, stream>>>(feat, w, nbr, nullptr, wsB, out, N);
  } else {
    mink_conv<0><<<blocks, 256, 0, stream>>>(feat, w, nbr, nullptr, nullptr, out, N);
  }
}